// Round 1
// 221.845 us; speedup vs baseline: 1.1912x; 1.1912x over previous
//
#include <hip/hip_runtime.h>

// ============================================================================
// FusedConv: per-edge MLP (32->256->256->768-slice) + small tensor contraction.
// bf16 MFMA (16x16x32) for the three GEMMs, fp32 accumulate, fused per
// 32-edge tile through LDS.
//
// This revision targets the latency/serialization bottleneck (prev: 200us
// fused, MfmaUtil 7%, VALUBusy 31%, Occ 22.5%, 12 barriers/block @3 blk/CU):
//   - 3 barriers/block (was 12): per-wave rp scratch needs no barrier
//     (same-wave LDS write->read is ordered); h2 overwrites h1 region.
//   - LDS 45568 -> 40960 B  => 4 blocks/CU (16 waves), launch_bounds(256,4).
//   - gelu: branchless exp2-based tanh form (~7 VALU ops) instead of erff
//     (~30-op branchy libm). |err| <= ~1e-3, below bf16 quantization noise.
//   - tmp stored [J][e][4] bf16: b64 conflict-free reads in contraction;
//     rp stored [J][e] bf16 with e-block xor swizzle: b64 writes, 2-way reads.
//   - edges bf16 cast folded into G1 (prep pass now weights-only).
//   - per-wave output accumulated in regs, stored once as 3x f32x4.
//
// LDS map (40960 B):
//   hS    [    0..16384): h1 then h2, 32 rows x 512 B, 16B-chunk xor swizzle
//   tmpS  [16384..28672): tmp[J=48][e=32][4] bf16 (d=3 + pad)
//   auxS  [28672..40960): staging featsb[32][50]+basisb[32][27] (phase A),
//                         then per-wave rpT[48][32] bf16 w/ swizzle (phase B)
// ============================================================================

typedef __bf16 bf16x8 __attribute__((ext_vector_type(8)));
typedef __bf16 bf16x4 __attribute__((ext_vector_type(4)));
typedef float f32x4 __attribute__((ext_vector_type(4)));

#define TE 32
#define E_TOT 65536

__device__ __forceinline__ f32x4 mfma16(bf16x8 a, bf16x8 b, f32x4 c) {
    return __builtin_amdgcn_mfma_f32_16x16x32_bf16(a, b, c, 0, 0, 0);
}

__device__ __forceinline__ float gelu_f(float x) {
    // tanh-form GELU: x * sigmoid(1.5957691*x + 0.0713548*x^3),
    // as x / (1 + exp2(-(2.3022082*x + 0.10294345*x^3))). Branchless,
    // 2 transcendentals. Handles +-inf limits correctly (exp2->0/inf).
    float u = x * x;
    float t = x * fmaf(u, 0.10294345f, 2.3022082f);
    return x * __builtin_amdgcn_rcpf(1.0f + __builtin_amdgcn_exp2f(-t));
}

// ---- ws layout (bytes) ----
#define WS_W1T   0u         // 256 x 32  bf16 (n-major)   16384 B
#define WS_W2T   16384u     // 256 x 256 bf16 (n-major)  131072 B
#define WS_W3KT  147456u    // 768 x 256 bf16 (n-major)  393216 B

#define N_W1T  8192
#define N_W2T  65536
#define N_W3KT 196608
#define PREP_TOT (N_W1T + N_W2T + N_W3KT)

__global__ __launch_bounds__(256) void prep_kernel(
    const float* __restrict__ W1, const float* __restrict__ W2,
    const float* __restrict__ W3,
    __bf16* __restrict__ W1T, __bf16* __restrict__ W2T,
    __bf16* __restrict__ W3kT)
{
    int stride = gridDim.x * blockDim.x;
    for (int idx = blockIdx.x * blockDim.x + threadIdx.x; idx < PREP_TOT; idx += stride) {
        if (idx < N_W1T) {
            int n = idx >> 5, k = idx & 31;
            W1T[idx] = (__bf16)W1[k * 256 + n];
        } else if (idx < N_W1T + N_W2T) {
            int t = idx - N_W1T; int n = t >> 8, k = t & 255;
            W2T[t] = (__bf16)W2[k * 256 + n];
        } else {
            int t = idx - (N_W1T + N_W2T); int n = t >> 8, k = t & 255;
            W3kT[t] = (__bf16)W3[k * 1536 + 768 + n];
        }
    }
}

// A-frag layout: lane holds A[m=lane&15][k=(lane>>4)*8 + j], j=0..7
// B-frag layout: lane holds B[k=(lane>>4)*8 + j][n=lane&15]
// C/D layout:    element (row=(lane>>4)*4 + reg, col=lane&15)
__global__ __launch_bounds__(256, 4) void fused_kernel(
    const float* __restrict__ edges, const __bf16* __restrict__ W1T,
    const __bf16* __restrict__ W2T, const __bf16* __restrict__ W3kT,
    const float* __restrict__ b1, const float* __restrict__ b2,
    const float* __restrict__ feats, const float* __restrict__ basis,
    float* __restrict__ out)
{
    __shared__ __align__(16) unsigned char smem[40960];
    unsigned char* hS   = smem;             // 16384 B: h1, then h2
    unsigned char* tmpS = smem + 16384;     // 12288 B: tmp[J][e][4]
    unsigned char* auxS = smem + 28672;     // 12288 B: staging / rpT
    __bf16* featsb = (__bf16*)auxS;           // [32][50] padded (3200 B)
    __bf16* basisb = (__bf16*)(auxS + 3200);  // [32][27]        (1728 B)

    const int tid = threadIdx.x;
    const int w = tid >> 6;       // wave 0..3
    const int l = tid & 63;
    const int c = l & 15;
    const int q = l >> 4;         // 0..3
    const int eb = blockIdx.x * TE;

    const f32x4 zero = {0.f, 0.f, 0.f, 0.f};

    // ---- stage feats/basis into aux (issue global loads early) -------------
    #pragma unroll
    for (int it = 0; it < 6; ++it) {
        int idx = tid + it * 256;             // 0..1535
        int e = idx / 48, r = idx - e * 48;
        featsb[e * 50 + r] = (__bf16)feats[(size_t)eb * 48 + idx];
    }
    #pragma unroll
    for (int it = 0; it < 4; ++it) {
        int idx = tid + it * 256;             // 0..1023 (need 864)
        if (idx < 864) basisb[idx] = (__bf16)basis[(size_t)eb * 27 + idx];
    }

    // ---------------- G1: h1 = gelu(edges @ W1 + b1), K=32 ------------------
    // Load fp32 edges directly, convert in-register (prep no longer touches
    // the 8.4MB edges array).
    const float* er0 = edges + (size_t)(eb + c) * 32 + q * 8;
    const float* er1 = edges + (size_t)(eb + 16 + c) * 32 + q * 8;
    f32x4 e00 = *(const f32x4*)er0;
    f32x4 e01 = *(const f32x4*)(er0 + 4);
    f32x4 e10 = *(const f32x4*)er1;
    f32x4 e11 = *(const f32x4*)(er1 + 4);
    bf16x8 a0, a1;
    #pragma unroll
    for (int j = 0; j < 4; ++j) {
        a0[j] = (__bf16)e00[j]; a0[j + 4] = (__bf16)e01[j];
        a1[j] = (__bf16)e10[j]; a1[j + 4] = (__bf16)e11[j];
    }

    f32x4 acc1[2][4];
    #pragma unroll
    for (int mt = 0; mt < 2; ++mt)
        #pragma unroll
        for (int nt = 0; nt < 4; ++nt) acc1[mt][nt] = zero;

    #pragma unroll
    for (int nt = 0; nt < 4; ++nt) {
        int col = w * 64 + nt * 16 + c;
        bf16x8 bf = *(const bf16x8*)(W1T + col * 32 + q * 8);
        acc1[0][nt] = mfma16(a0, bf, acc1[0][nt]);
        acc1[1][nt] = mfma16(a1, bf, acc1[1][nt]);
    }
    #pragma unroll
    for (int nt = 0; nt < 4; ++nt) {
        int col = w * 64 + nt * 16 + c;
        float bias = b1[col];
        #pragma unroll
        for (int mt = 0; mt < 2; ++mt)
            #pragma unroll
            for (int r = 0; r < 4; ++r) {
                int e = mt * 16 + q * 4 + r;
                float g = gelu_f(acc1[mt][nt][r] + bias);
                int chunk = (col >> 3) ^ (e & 7);
                *(__bf16*)(hS + e * 512 + chunk * 16 + (col & 7) * 2) = (__bf16)g;
            }
    }
    __syncthreads();   // S1: h1 + staged feats/basis visible

    // ---------------- G2: h2 = gelu(h1 @ W2 + b2), K=256 --------------------
    f32x4 acc2[2][4];
    #pragma unroll
    for (int mt = 0; mt < 2; ++mt)
        #pragma unroll
        for (int nt = 0; nt < 4; ++nt) acc2[mt][nt] = zero;

    #pragma unroll
    for (int ks = 0; ks < 8; ++ks) {
        bf16x8 af0, af1;
        { int m = c;      int chunk = (ks * 4 + q) ^ (m & 7); af0 = *(const bf16x8*)(hS + m * 512 + chunk * 16); }
        { int m = 16 + c; int chunk = (ks * 4 + q) ^ (m & 7); af1 = *(const bf16x8*)(hS + m * 512 + chunk * 16); }
        #pragma unroll
        for (int nt = 0; nt < 4; ++nt) {
            int col = w * 64 + nt * 16 + c;
            bf16x8 bf = *(const bf16x8*)(W2T + col * 256 + ks * 32 + q * 8);
            acc2[0][nt] = mfma16(af0, bf, acc2[0][nt]);
            acc2[1][nt] = mfma16(af1, bf, acc2[1][nt]);
        }
    }

    // ------- build tmp[J][e][4] bf16 from staged feats/basis ----------------
    // thread owns edge e = tid&31, J = (tid>>5) + 8k, k=0..5; writes b64.
    {
        int e = tid & 31;
        int j0 = tid >> 5;
        const __bf16* fr = featsb + e * 50;
        const __bf16* br = basisb + e * 27;
        #pragma unroll
        for (int k2 = 0; k2 < 6; ++k2) {
            int J = j0 + k2 * 8;
            int i0 = J / 3;
            int nf = J - i0 * 3;
            float f0 = (float)fr[i0 * 3 + 0];
            float f1 = (float)fr[i0 * 3 + 1];
            float f2 = (float)fr[i0 * 3 + 2];
            const __bf16* bp = br + nf * 3;
            bf16x4 v;
            #pragma unroll
            for (int d = 0; d < 3; ++d) {
                float s = f0 * (float)bp[d] + f1 * (float)bp[9 + d] + f2 * (float)bp[18 + d];
                v[d] = (__bf16)s;
            }
            v[3] = (__bf16)0.f;
            *(bf16x4*)(tmpS + J * 256 + e * 8) = v;
        }
    }
    __syncthreads();   // S2: all h1 reads done (safe to overwrite with h2)

    #pragma unroll
    for (int nt = 0; nt < 4; ++nt) {
        int col = w * 64 + nt * 16 + c;
        float bias = b2[col];
        #pragma unroll
        for (int mt = 0; mt < 2; ++mt)
            #pragma unroll
            for (int r = 0; r < 4; ++r) {
                int e = mt * 16 + q * 4 + r;
                float g = gelu_f(acc2[mt][nt][r] + bias);
                int chunk = (col >> 3) ^ (e & 7);
                *(__bf16*)(hS + e * 512 + chunk * 16 + (col & 7) * 2) = (__bf16)g;
            }
    }
    __syncthreads();   // S3: h2 + tmp visible; aux staging dead from here on

    // ------- G3 (rp = h2 @ W3k) fused with final contraction, per o ----------
    // rpT per-wave scratch: [48 J][32 e] bf16 rows of 64B, e-block (e>>2)
    // xor-swizzled by (J&7). Same-wave write->read: NO barrier needed.
    unsigned char* rb = auxS + w * 3072;
    const int le = l & 31, hv = l >> 5;
    float p[12];
    #pragma unroll
    for (int i = 0; i < 12; ++i) p[i] = 0.f;

    #pragma unroll 1
    for (int oi = 0; oi < 4; ++oi) {
        int o = w * 4 + oi;          // wave owns o in {4w..4w+3}
        f32x4 acc3[2][3];
        #pragma unroll
        for (int mt = 0; mt < 2; ++mt)
            #pragma unroll
            for (int nt = 0; nt < 3; ++nt) acc3[mt][nt] = zero;

        #pragma unroll
        for (int ks = 0; ks < 8; ++ks) {
            bf16x8 af0, af1;
            { int m = c;      int chunk = (ks * 4 + q) ^ (m & 7); af0 = *(const bf16x8*)(hS + m * 512 + chunk * 16); }
            { int m = 16 + c; int chunk = (ks * 4 + q) ^ (m & 7); af1 = *(const bf16x8*)(hS + m * 512 + chunk * 16); }
            #pragma unroll
            for (int nt = 0; nt < 3; ++nt) {
                int col = o * 48 + nt * 16 + c;
                bf16x8 bf = *(const bf16x8*)(W3kT + col * 256 + ks * 32 + q * 8);
                acc3[0][nt] = mfma16(af0, bf, acc3[0][nt]);
                acc3[1][nt] = mfma16(af1, bf, acc3[1][nt]);
            }
        }
        // spill rp tile (32e x 48J) to per-wave LDS as b64 writes
        #pragma unroll
        for (int nt = 0; nt < 3; ++nt) {
            int J = nt * 16 + c;
            #pragma unroll
            for (int mt = 0; mt < 2; ++mt) {
                bf16x4 v;
                v[0] = (__bf16)acc3[mt][nt][0];
                v[1] = (__bf16)acc3[mt][nt][1];
                v[2] = (__bf16)acc3[mt][nt][2];
                v[3] = (__bf16)acc3[mt][nt][3];
                *(bf16x4*)(rb + J * 64 + (((mt * 4 + q) ^ (J & 7)) << 3)) = v;
            }
        }
        // out[e][o][d] = sum_J rp[e][J] * tmp[J][e][d]; 2 lanes per edge.
        // Same-wave LDS consumption: ordered by the per-wave DS queue.
        float s0 = 0.f, s1 = 0.f, s2 = 0.f;
        #pragma unroll
        for (int jj = 0; jj < 24; ++jj) {
            int J = hv * 24 + jj;
            float rv = (float)*(const __bf16*)(rb + J * 64 +
                           ((((le >> 2) ^ (J & 7)) << 3)) + (le & 3) * 2);
            bf16x4 tv = *(const bf16x4*)(tmpS + J * 256 + le * 8);
            s0 = fmaf(rv, (float)tv[0], s0);
            s1 = fmaf(rv, (float)tv[1], s1);
            s2 = fmaf(rv, (float)tv[2], s2);
        }
        s0 += __shfl_xor(s0, 32, 64);
        s1 += __shfl_xor(s1, 32, 64);
        s2 += __shfl_xor(s2, 32, 64);
        p[oi * 3 + 0] = s0; p[oi * 3 + 1] = s1; p[oi * 3 + 2] = s2;
    }

    if (hv == 0) {
        float* op = out + (size_t)(eb + le) * 48 + w * 12;
        f32x4 o0 = {p[0], p[1], p[2],  p[3]};
        f32x4 o1 = {p[4], p[5], p[6],  p[7]};
        f32x4 o2 = {p[8], p[9], p[10], p[11]};
        *(f32x4*)(op)     = o0;
        *(f32x4*)(op + 4) = o1;
        *(f32x4*)(op + 8) = o2;
    }
}

extern "C" void kernel_launch(void* const* d_in, const int* in_sizes, int n_in,
                              void* d_out, int out_size, void* d_ws, size_t ws_size,
                              hipStream_t stream) {
    const float* edges = (const float*)d_in[0];
    const float* feats = (const float*)d_in[1];
    const float* basis = (const float*)d_in[2];
    const float* W1    = (const float*)d_in[3];
    const float* b1    = (const float*)d_in[4];
    const float* W2    = (const float*)d_in[5];
    const float* b2    = (const float*)d_in[6];
    const float* W3    = (const float*)d_in[7];
    float* out = (float*)d_out;

    __bf16* W1T  = (__bf16*)((char*)d_ws + WS_W1T);
    __bf16* W2T  = (__bf16*)((char*)d_ws + WS_W2T);
    __bf16* W3kT = (__bf16*)((char*)d_ws + WS_W3KT);

    prep_kernel<<<PREP_TOT / 256, 256, 0, stream>>>(W1, W2, W3, W1T, W2T, W3kT);
    fused_kernel<<<E_TOT / TE, 256, 0, stream>>>(edges, W1T, W2T, W3kT, b1, b2,
                                                 feats, basis, out);
}

// Round 2
// 154.930 us; speedup vs baseline: 1.7056x; 1.4319x over previous
//
#include <hip/hip_runtime.h>

// ============================================================================
// FusedConv: per-edge MLP (32->256->256->768-slice) + small tensor contraction.
// bf16 MFMA (16x16x32) for the three GEMMs, fp32 accumulate, fused per
// 32-edge tile through LDS.
//
// Round-2 revision targets per-wave memory-latency stalls (prev: 164us fused,
// MfmaUtil 8.6%, VALUBusy 19.7%, Occ 44%, VGPR 64 => zero prefetch depth):
//   - Weights pre-packed in FRAGMENT order (W1F/W2F/W3F): a wave's B-frag
//     load is base + lane*16B -> one coalesced 1KB transaction (was 16
//     scattered 64B lines spread over 8KB).
//   - Explicit double-buffered B-fragments in the G2/G3 ks-loops; next-oi
//     first fragments prefetched before the contraction so contraction VALU
//     hides the next MFMA phase's L2 latency. Uses the idle VGPR headroom.
//   - Per-oi direct global stores (removes runtime-indexed p[] scratch risk).
//   - prep kernel rewritten read-coalesced (src-linear, scatter on write).
//
// LDS map (40960 B, 4 blocks/CU):
//   hS    [    0..16384): h1 then h2, 32 rows x 512 B, 16B-chunk xor swizzle
//   tmpS  [16384..28672): tmp[J=48][e=32][4] bf16 (d=3 + pad)
//   auxS  [28672..40960): staging featsb[32][50]+basisb[32][27] (phase A),
//                         then per-wave rpT[48][32] bf16 w/ swizzle (phase B)
// ============================================================================

typedef __bf16 bf16x8 __attribute__((ext_vector_type(8)));
typedef __bf16 bf16x4 __attribute__((ext_vector_type(4)));
typedef float f32x4 __attribute__((ext_vector_type(4)));

#define TE 32
#define E_TOT 65536

__device__ __forceinline__ f32x4 mfma16(bf16x8 a, bf16x8 b, f32x4 c) {
    return __builtin_amdgcn_mfma_f32_16x16x32_bf16(a, b, c, 0, 0, 0);
}

__device__ __forceinline__ float gelu_f(float x) {
    // tanh-form GELU via exp2; branchless, 2 transcendentals.
    float u = x * x;
    float t = x * fmaf(u, 0.10294345f, 2.3022082f);
    return x * __builtin_amdgcn_rcpf(1.0f + __builtin_amdgcn_exp2f(-t));
}

// ---- ws layout (bytes): fragment-ordered weights ----
// Fragment for tile t (cols 16t..16t+15), k-step ks: lane l holds
// B[k = ks*32 + (l>>4)*8 + j][col = 16t + (l&15)], j=0..7.
#define WS_W1F 0u        // 16 t x 64 x 8 bf16          16384 B
#define WS_W2F 16384u    // 16 t x 8 ks x 64 x 8       131072 B
#define WS_W3F 147456u   // 48 t x 8 ks x 64 x 8       393216 B

#define N_W1F 8192
#define N_W2F 65536
#define N_W3F 196608
#define PREP_TOT (N_W1F + N_W2F + N_W3F)

__global__ __launch_bounds__(256) void prep_kernel(
    const float* __restrict__ W1, const float* __restrict__ W2,
    const float* __restrict__ W3,
    __bf16* __restrict__ W1F, __bf16* __restrict__ W2F,
    __bf16* __restrict__ W3F)
{
    int stride = gridDim.x * blockDim.x;
    for (int idx = blockIdx.x * blockDim.x + threadIdx.x; idx < PREP_TOT; idx += stride) {
        if (idx < N_W1F) {
            // src-linear over W1 (32 x 256)
            int k = idx >> 8, col = idx & 255;
            int t = col >> 4, cc = col & 15, q = k >> 3, j = k & 7;
            W1F[((t * 64 + q * 16 + cc) << 3) + j] = (__bf16)W1[idx];
        } else if (idx < N_W1F + N_W2F) {
            // src-linear over W2 (256 x 256)
            int t2 = idx - N_W1F;
            int k = t2 >> 8, col = t2 & 255;
            int ks = k >> 5, q = (k >> 3) & 3, j = k & 7;
            int t = col >> 4, cc = col & 15;
            W2F[(((t * 8 + ks) * 64 + q * 16 + cc) << 3) + j] = (__bf16)W2[t2];
        } else {
            // src-linear over the W3 768-col slice (256 x 768)
            int t3 = idx - (N_W1F + N_W2F);
            int k = t3 / 768, col = t3 - k * 768;
            int ks = k >> 5, q = (k >> 3) & 3, j = k & 7;
            int t = col >> 4, cc = col & 15;
            W3F[(((t * 8 + ks) * 64 + q * 16 + cc) << 3) + j] =
                (__bf16)W3[k * 1536 + 768 + col];
        }
    }
}

// A-frag layout: lane holds A[m=lane&15][k=(lane>>4)*8 + j], j=0..7
// B-frag layout: lane holds B[k=(lane>>4)*8 + j][n=lane&15]
// C/D layout:    element (row=(lane>>4)*4 + reg, col=lane&15)
__global__ __launch_bounds__(256, 4) void fused_kernel(
    const float* __restrict__ edges, const __bf16* __restrict__ W1F,
    const __bf16* __restrict__ W2F, const __bf16* __restrict__ W3F,
    const float* __restrict__ b1, const float* __restrict__ b2,
    const float* __restrict__ feats, const float* __restrict__ basis,
    float* __restrict__ out)
{
    __shared__ __align__(16) unsigned char smem[40960];
    unsigned char* hS   = smem;             // 16384 B: h1, then h2
    unsigned char* tmpS = smem + 16384;     // 12288 B: tmp[J][e][4]
    unsigned char* auxS = smem + 28672;     // 12288 B: staging / rpT
    __bf16* featsb = (__bf16*)auxS;           // [32][50] padded (3200 B)
    __bf16* basisb = (__bf16*)(auxS + 3200);  // [32][27]        (1728 B)

    const int tid = threadIdx.x;
    const int w = tid >> 6;       // wave 0..3
    const int l = tid & 63;
    const int c = l & 15;
    const int q = l >> 4;         // 0..3
    const int eb = blockIdx.x * TE;

    const f32x4 zero = {0.f, 0.f, 0.f, 0.f};

    // ---- stage feats/basis into aux (issue global loads early) -------------
    #pragma unroll
    for (int it = 0; it < 6; ++it) {
        int idx = tid + it * 256;             // 0..1535
        int e = idx / 48, r = idx - e * 48;
        featsb[e * 50 + r] = (__bf16)feats[(size_t)eb * 48 + idx];
    }
    #pragma unroll
    for (int it = 0; it < 4; ++it) {
        int idx = tid + it * 256;             // 0..1023 (need 864)
        if (idx < 864) basisb[idx] = (__bf16)basis[(size_t)eb * 27 + idx];
    }

    // ---------------- G1: h1 = gelu(edges @ W1 + b1), K=32 ------------------
    const float* er0 = edges + (size_t)(eb + c) * 32 + q * 8;
    const float* er1 = edges + (size_t)(eb + 16 + c) * 32 + q * 8;
    f32x4 e00 = *(const f32x4*)er0;
    f32x4 e01 = *(const f32x4*)(er0 + 4);
    f32x4 e10 = *(const f32x4*)er1;
    f32x4 e11 = *(const f32x4*)(er1 + 4);
    bf16x8 a0, a1;
    #pragma unroll
    for (int j = 0; j < 4; ++j) {
        a0[j] = (__bf16)e00[j]; a0[j + 4] = (__bf16)e01[j];
        a1[j] = (__bf16)e10[j]; a1[j + 4] = (__bf16)e11[j];
    }

    f32x4 acc1[2][4];
    #pragma unroll
    for (int mt = 0; mt < 2; ++mt)
        #pragma unroll
        for (int nt = 0; nt < 4; ++nt) acc1[mt][nt] = zero;

    // coalesced fragment loads: base + l*16B
    const __bf16* W1Fw = W1F + (size_t)(w * 4) * 512 + (size_t)l * 8;
    #pragma unroll
    for (int nt = 0; nt < 4; ++nt) {
        bf16x8 bf = *(const bf16x8*)(W1Fw + nt * 512);
        acc1[0][nt] = mfma16(a0, bf, acc1[0][nt]);
        acc1[1][nt] = mfma16(a1, bf, acc1[1][nt]);
    }
    #pragma unroll
    for (int nt = 0; nt < 4; ++nt) {
        int col = w * 64 + nt * 16 + c;
        float bias = b1[col];
        #pragma unroll
        for (int mt = 0; mt < 2; ++mt)
            #pragma unroll
            for (int r = 0; r < 4; ++r) {
                int e = mt * 16 + q * 4 + r;
                float g = gelu_f(acc1[mt][nt][r] + bias);
                int chunk = (col >> 3) ^ (e & 7);
                *(__bf16*)(hS + e * 512 + chunk * 16 + (col & 7) * 2) = (__bf16)g;
            }
    }
    __syncthreads();   // S1: h1 + staged feats/basis visible

    // ---------------- G2: h2 = gelu(h1 @ W2 + b2), K=256 --------------------
    f32x4 acc2[2][4];
    #pragma unroll
    for (int mt = 0; mt < 2; ++mt)
        #pragma unroll
        for (int nt = 0; nt < 4; ++nt) acc2[mt][nt] = zero;

    const __bf16* W2Fw = W2F + (size_t)(w * 4) * 4096 + (size_t)l * 8;
    {
        bf16x8 cb[4], nb[4];
        #pragma unroll
        for (int nt = 0; nt < 4; ++nt)
            cb[nt] = *(const bf16x8*)(W2Fw + nt * 4096);
        #pragma unroll
        for (int ks = 0; ks < 8; ++ks) {
            if (ks < 7) {
                #pragma unroll
                for (int nt = 0; nt < 4; ++nt)
                    nb[nt] = *(const bf16x8*)(W2Fw + nt * 4096 + (ks + 1) * 512);
            }
            bf16x8 af0, af1;
            { int m = c;      int chunk = (ks * 4 + q) ^ (m & 7); af0 = *(const bf16x8*)(hS + m * 512 + chunk * 16); }
            { int m = 16 + c; int chunk = (ks * 4 + q) ^ (m & 7); af1 = *(const bf16x8*)(hS + m * 512 + chunk * 16); }
            #pragma unroll
            for (int nt = 0; nt < 4; ++nt) {
                acc2[0][nt] = mfma16(af0, cb[nt], acc2[0][nt]);
                acc2[1][nt] = mfma16(af1, cb[nt], acc2[1][nt]);
            }
            if (ks < 7) {
                #pragma unroll
                for (int nt = 0; nt < 4; ++nt) cb[nt] = nb[nt];
            }
        }
    }

    // ------- build tmp[J][e][4] bf16 from staged feats/basis ----------------
    {
        int e = tid & 31;
        int j0 = tid >> 5;
        const __bf16* fr = featsb + e * 50;
        const __bf16* br = basisb + e * 27;
        #pragma unroll
        for (int k2 = 0; k2 < 6; ++k2) {
            int J = j0 + k2 * 8;
            int i0 = J / 3;
            int nf = J - i0 * 3;
            float f0 = (float)fr[i0 * 3 + 0];
            float f1 = (float)fr[i0 * 3 + 1];
            float f2 = (float)fr[i0 * 3 + 2];
            const __bf16* bp = br + nf * 3;
            bf16x4 v;
            #pragma unroll
            for (int d = 0; d < 3; ++d) {
                float s = f0 * (float)bp[d] + f1 * (float)bp[9 + d] + f2 * (float)bp[18 + d];
                v[d] = (__bf16)s;
            }
            v[3] = (__bf16)0.f;
            *(bf16x4*)(tmpS + J * 256 + e * 8) = v;
        }
    }
    __syncthreads();   // S2: all h1 reads done (safe to overwrite with h2)

    #pragma unroll
    for (int nt = 0; nt < 4; ++nt) {
        int col = w * 64 + nt * 16 + c;
        float bias = b2[col];
        #pragma unroll
        for (int mt = 0; mt < 2; ++mt)
            #pragma unroll
            for (int r = 0; r < 4; ++r) {
                int e = mt * 16 + q * 4 + r;
                float g = gelu_f(acc2[mt][nt][r] + bias);
                int chunk = (col >> 3) ^ (e & 7);
                *(__bf16*)(hS + e * 512 + chunk * 16 + (col & 7) * 2) = (__bf16)g;
            }
    }
    __syncthreads();   // S3: h2 + tmp visible; aux staging dead from here on

    // ------- G3 (rp = h2 @ W3k) fused with final contraction, per o ----------
    unsigned char* rb = auxS + w * 3072;
    const int le = l & 31, hv = l >> 5;
    const __bf16* W3Fw = W3F + (size_t)l * 8;

    // prefetch first o's first-ks fragments
    bf16x8 pre[3];
    #pragma unroll
    for (int nt = 0; nt < 3; ++nt)
        pre[nt] = *(const bf16x8*)(W3Fw + (size_t)((w * 4) * 3 + nt) * 4096);

    #pragma unroll 1
    for (int oi = 0; oi < 4; ++oi) {
        int o = w * 4 + oi;          // wave owns o in {4w..4w+3}
        const __bf16* W3Fo = W3Fw + (size_t)(o * 3) * 4096;
        f32x4 acc3[2][3];
        #pragma unroll
        for (int mt = 0; mt < 2; ++mt)
            #pragma unroll
            for (int nt = 0; nt < 3; ++nt) acc3[mt][nt] = zero;

        bf16x8 cb[3], nb[3];
        #pragma unroll
        for (int nt = 0; nt < 3; ++nt) cb[nt] = pre[nt];

        #pragma unroll
        for (int ks = 0; ks < 8; ++ks) {
            if (ks < 7) {
                #pragma unroll
                for (int nt = 0; nt < 3; ++nt)
                    nb[nt] = *(const bf16x8*)(W3Fo + nt * 4096 + (ks + 1) * 512);
            }
            bf16x8 af0, af1;
            { int m = c;      int chunk = (ks * 4 + q) ^ (m & 7); af0 = *(const bf16x8*)(hS + m * 512 + chunk * 16); }
            { int m = 16 + c; int chunk = (ks * 4 + q) ^ (m & 7); af1 = *(const bf16x8*)(hS + m * 512 + chunk * 16); }
            #pragma unroll
            for (int nt = 0; nt < 3; ++nt) {
                acc3[0][nt] = mfma16(af0, cb[nt], acc3[0][nt]);
                acc3[1][nt] = mfma16(af1, cb[nt], acc3[1][nt]);
            }
            if (ks < 7) {
                #pragma unroll
                for (int nt = 0; nt < 3; ++nt) cb[nt] = nb[nt];
            }
        }
        // spill rp tile (32e x 48J) to per-wave LDS as b64 writes
        #pragma unroll
        for (int nt = 0; nt < 3; ++nt) {
            int J = nt * 16 + c;
            #pragma unroll
            for (int mt = 0; mt < 2; ++mt) {
                bf16x4 v;
                v[0] = (__bf16)acc3[mt][nt][0];
                v[1] = (__bf16)acc3[mt][nt][1];
                v[2] = (__bf16)acc3[mt][nt][2];
                v[3] = (__bf16)acc3[mt][nt][3];
                *(bf16x4*)(rb + J * 64 + (((mt * 4 + q) ^ (J & 7)) << 3)) = v;
            }
        }
        // prefetch next o's first-ks fragments; in flight during contraction
        {
            int on = (oi < 3) ? (o + 1) : o;
            #pragma unroll
            for (int nt = 0; nt < 3; ++nt)
                pre[nt] = *(const bf16x8*)(W3Fw + (size_t)(on * 3 + nt) * 4096);
        }
        // out[e][o][d] = sum_J rp[e][J] * tmp[J][e][d]; 2 lanes per edge.
        float s0 = 0.f, s1 = 0.f, s2 = 0.f;
        #pragma unroll
        for (int jj = 0; jj < 24; ++jj) {
            int J = hv * 24 + jj;
            float rv = (float)*(const __bf16*)(rb + J * 64 +
                           ((((le >> 2) ^ (J & 7)) << 3)) + (le & 3) * 2);
            bf16x4 tv = *(const bf16x4*)(tmpS + J * 256 + le * 8);
            s0 = fmaf(rv, (float)tv[0], s0);
            s1 = fmaf(rv, (float)tv[1], s1);
            s2 = fmaf(rv, (float)tv[2], s2);
        }
        s0 += __shfl_xor(s0, 32, 64);
        s1 += __shfl_xor(s1, 32, 64);
        s2 += __shfl_xor(s2, 32, 64);
        if (hv == 0) {
            float* op = out + (size_t)(eb + le) * 48 + o * 3;
            op[0] = s0; op[1] = s1; op[2] = s2;
        }
    }
}

extern "C" void kernel_launch(void* const* d_in, const int* in_sizes, int n_in,
                              void* d_out, int out_size, void* d_ws, size_t ws_size,
                              hipStream_t stream) {
    const float* edges = (const float*)d_in[0];
    const float* feats = (const float*)d_in[1];
    const float* basis = (const float*)d_in[2];
    const float* W1    = (const float*)d_in[3];
    const float* b1    = (const float*)d_in[4];
    const float* W2    = (const float*)d_in[5];
    const float* b2    = (const float*)d_in[6];
    const float* W3    = (const float*)d_in[7];
    float* out = (float*)d_out;

    __bf16* W1F = (__bf16*)((char*)d_ws + WS_W1F);
    __bf16* W2F = (__bf16*)((char*)d_ws + WS_W2F);
    __bf16* W3F = (__bf16*)((char*)d_ws + WS_W3F);

    prep_kernel<<<PREP_TOT / 256, 256, 0, stream>>>(W1, W2, W3, W1F, W2F, W3F);
    fused_kernel<<<E_TOT / TE, 256, 0, stream>>>(edges, W1F, W2F, W3F, b1, b2,
                                                 feats, basis, out);
}